// Round 10
// baseline (75.762 us; speedup 1.0000x reference)
//
#include <hip/hip_runtime.h>
#include <stdint.h>

typedef unsigned long long u64;
typedef __attribute__((ext_vector_type(8))) short short8;   // 8 x bf16 (4 VGPR)
typedef __attribute__((ext_vector_type(4))) float f32x4;    // MFMA C/D frag

#define B_ 32
#define N_ 512
#define FIN_ 80
#define FH_ 50
#define FO_ 80
#define CAT_ 150
#define KP_ 160   // padded K for layer-2 (150 + 9 zero + 1 ones@159)
#define NP_ 96    // WoutT leading dim (cols 80..95 unused)

__device__ inline unsigned short f2bf(float f) {  // RNE float -> bf16 bits
  unsigned u = __float_as_uint(f);
  u += 0x7fffu + ((u >> 16) & 1u);
  return (unsigned short)(u >> 16);
}

__device__ inline unsigned nib4(int4 v) {
  return (v.x != 0 ? 1u : 0u) | (v.y != 0 ? 2u : 0u) |
         (v.z != 0 ? 4u : 0u) | (v.w != 0 ? 8u : 0u);
}

// A-fragment builder: p = exp(min(lrelu(e1+e2),60)) masked, bf16
__device__ inline short8 build_af(const float* e2s, float e1r, u64 word,
                                  int jb, int shift) {
  short8 af;
  unsigned b0 = (unsigned)(word >> shift) & 0xffu;
  float4 va = *(const float4*)&e2s[jb];
  float4 vb = *(const float4*)&e2s[jb + 4];
  float ev[8] = {va.x, va.y, va.z, va.w, vb.x, vb.y, vb.z, vb.w};
  #pragma unroll
  for (int e = 0; e < 8; ++e) {
    float sv = e1r + ev[e];
    sv = fmaxf(sv, 0.2f * sv);
    sv = fminf(sv, 60.f);
    float arg = ((b0 >> e) & 1u) ? sv : -1e30f;
    af[e] = (short)f2bf(__expf(arg));
  }
  return af;
}

// ---------- kA: 0..2047 mask | 2048..2062 WoutT | 2063 wv | 2064..2831 k1-MFMA ----
__global__ __launch_bounds__(256) void kA(const float* __restrict__ h,
                                          const int* __restrict__ adj,
                                          const float* __restrict__ Ws,
                                          const float* __restrict__ attn_a,
                                          const float* __restrict__ Wout,
                                          const float* __restrict__ a_out,
                                          unsigned short* __restrict__ whT,
                                          float* __restrict__ e1h,
                                          float* __restrict__ e2h,
                                          u64* __restrict__ maskw,
                                          unsigned short* __restrict__ WoutT,
                                          float* __restrict__ wv1,
                                          float* __restrict__ wv2) {
  __shared__ __align__(16) unsigned short un[64 * 104];    // h bf16; reused as tbT[64][72]
  __shared__ __align__(16) unsigned short bstage[12 * 512]; // Ws B-frags
  __shared__ unsigned short sm[256];                        // mask bounce
  const int t = threadIdx.x;
  const int bid = blockIdx.x;

  if (bid < 2048) {  // ---- mask: 8 rows/block (round-9 pattern) ----
    const int r = t >> 5, s = t & 31;
    const int row = bid * 8 + r;
    const int4* src = (const int4*)(adj + (size_t)row * N_ + s * 16);
    int4 v0 = src[0], v1 = src[1], v2 = src[2], v3 = src[3];
    unsigned m = nib4(v0) | (nib4(v1) << 4) | (nib4(v2) << 8) | (nib4(v3) << 12);
    sm[t] = (unsigned short)m;
    __syncthreads();
    if (t < 64) {
      const int rr = t >> 3, w = t & 7;
      const unsigned short* p = &sm[rr * 32 + w * 4];
      u64 mm = (u64)p[0] | ((u64)p[1] << 16) | ((u64)p[2] << 32) | ((u64)p[3] << 48);
      maskw[(size_t)(bid * 8 + rr) * 8 + w] = mm;
    }
    return;
  }
  if (bid < 2063) {  // ---- WoutT[col 96][k 160] bf16: 1 uint2/thread ----
    const int i = (bid - 2048) * 256 + t;
    const int base = i * 4;
    const int col = base / KP_, k0 = base % KP_;
    unsigned short pk[4];
    #pragma unroll
    for (int e = 0; e < 4; ++e) {
      const int k = k0 + e;
      pk[e] = (col < FO_ && k < CAT_) ? f2bf(Wout[(size_t)k * FO_ + col]) : 0;
    }
    uint2 o;
    o.x = (unsigned)pk[0] | ((unsigned)pk[1] << 16);
    o.y = (unsigned)pk[2] | ((unsigned)pk[3] << 16);
    ((uint2*)WoutT)[i] = o;
    return;
  }
  if (bid == 2063) {  // ---- wv1/wv2[k] = Wout[k][:] . a_out halves ----
    if (t < CAT_) {
      const float4* wr = (const float4*)(Wout + (size_t)t * FO_);
      const float4* a1 = (const float4*)a_out;
      const float4* a2 = (const float4*)(a_out + FO_);
      float p1 = 0.f, p2 = 0.f;
      #pragma unroll
      for (int i = 0; i < 20; ++i) {
        float4 v = wr[i], x1 = a1[i], x2 = a2[i];
        p1 += v.x * x1.x + v.y * x1.y + v.z * x1.z + v.w * x1.w;
        p2 += v.x * x2.x + v.y * x2.y + v.z * x2.z + v.w * x2.w;
      }
      wv1[t] = p1; wv2[t] = p2;
    }
    return;
  }

  // ---- k1: Wh via MFMA, e1h/e2h from MFMA accs, whT emit ----
  int x = bid - 2064;
  const int rt = x & 7; x >>= 3;
  const int bb = x & 31; x >>= 5;
  const int hh = x;
  const int n0 = rt * 64;
  const float* hblk = h + ((size_t)bb * N_ + n0) * FIN_;
  const float* wsrc = Ws + (size_t)hh * FIN_ * FH_;

  for (int idx = t; idx < 64 * 13; idx += 256) {  // h tile bf16 [64][104]
    const int row = idx / 13, k0 = (idx - row * 13) * 8;
    short8 v8;
    if (k0 < FIN_) {
      float4 a = *(const float4*)(hblk + row * FIN_ + k0);
      float4 b = *(const float4*)(hblk + row * FIN_ + k0 + 4);
      v8[0] = (short)f2bf(a.x); v8[1] = (short)f2bf(a.y);
      v8[2] = (short)f2bf(a.z); v8[3] = (short)f2bf(a.w);
      v8[4] = (short)f2bf(b.x); v8[5] = (short)f2bf(b.y);
      v8[6] = (short)f2bf(b.z); v8[7] = (short)f2bf(b.w);
    } else {
      #pragma unroll
      for (int e = 0; e < 8; ++e) v8[e] = 0;
    }
    *(short8*)&un[row * 104 + k0] = v8;
  }
  for (int idx = t; idx < 768; idx += 256) {  // B-frags from Ws (L2-cached)
    const int f = idx >> 6, lf = idx & 63;
    const int ks = f >> 2, nt = f & 3;
    const int kb = ks * 32 + (lf >> 4) * 8, n = nt * 16 + (lf & 15);
    short8 v8;
    #pragma unroll
    for (int e = 0; e < 8; ++e) {
      const int k = kb + e;
      v8[e] = (k < FIN_ && n < FH_) ? (short)f2bf(wsrc[k * FH_ + n]) : (short)0;
    }
    *(short8*)&bstage[idx * 8] = v8;
  }
  __syncthreads();

  const int l = t & 63, wv = t >> 6, q = l >> 4, rl = l & 15;
  f32x4 acc[4];
  {
    short8 af[3];
    #pragma unroll
    for (int ks = 0; ks < 3; ++ks)
      af[ks] = *(const short8*)&un[(wv * 16 + rl) * 104 + ks * 32 + q * 8];
    #pragma unroll
    for (int nt = 0; nt < 4; ++nt) acc[nt] = (f32x4){0.f, 0.f, 0.f, 0.f};
    #pragma unroll
    for (int ks = 0; ks < 3; ++ks)
      #pragma unroll
      for (int nt = 0; nt < 4; ++nt)
        acc[nt] = __builtin_amdgcn_mfma_f32_16x16x32_bf16(
            af[ks], *(const short8*)&bstage[((ks * 4 + nt) * 64 + l) * 8], acc[nt], 0, 0, 0);
  }
  {  // e1/e2 from f32 accumulators: e[j] = sum_col Wh[j][col]*a[col]
    float a1v[4], a2v[4];
    #pragma unroll
    for (int c = 0; c < 4; ++c) {
      const int col = c * 16 + rl;
      a1v[c] = (col < FH_) ? attn_a[hh * 2 * FH_ + col] : 0.f;
      a2v[c] = (col < FH_) ? attn_a[hh * 2 * FH_ + FH_ + col] : 0.f;
    }
    #pragma unroll
    for (int r = 0; r < 4; ++r) {
      float p1 = acc[0][r] * a1v[0] + acc[1][r] * a1v[1] +
                 acc[2][r] * a1v[2] + acc[3][r] * a1v[3];
      float p2 = acc[0][r] * a2v[0] + acc[1][r] * a2v[1] +
                 acc[2][r] * a2v[2] + acc[3][r] * a2v[3];
      p1 += __shfl_xor(p1, 1); p1 += __shfl_xor(p1, 2);
      p1 += __shfl_xor(p1, 4); p1 += __shfl_xor(p1, 8);
      p2 += __shfl_xor(p2, 1); p2 += __shfl_xor(p2, 2);
      p2 += __shfl_xor(p2, 4); p2 += __shfl_xor(p2, 8);
      if (rl == 0) {
        size_t o = ((size_t)hh * B_ + bb) * N_ + n0 + wv * 16 + q * 4 + r;
        e1h[o] = p1; e2h[o] = p2;
      }
    }
  }
  __syncthreads();   // un reads done -> reuse as tbT
  unsigned short* tbT = un;  // [col][j], stride 72
  #pragma unroll
  for (int nt = 0; nt < 4; ++nt)
    #pragma unroll
    for (int r2 = 0; r2 < 4; ++r2)
      tbT[(nt * 16 + rl) * 72 + wv * 16 + q * 4 + r2] = f2bf(acc[nt][r2]);
  __syncthreads();
  {  // emit whT[col][j] coalesced; col 63 = ones (layer-1 denominator)
    const int col = t & 63, half = t >> 6;
    uint4 o0 = *(const uint4*)&tbT[col * 72 + half * 16];
    uint4 o1 = *(const uint4*)&tbT[col * 72 + half * 16 + 8];
    if (col == 63) {
      o0.x = o0.y = o0.z = o0.w = 0x3f803f80u;
      o1 = o0;
    }
    unsigned short* dst = whT + (((size_t)hh * B_ + bb) * 64 + col) * 512 + n0 + half * 16;
    *(uint4*)dst = o0;
    *(uint4*)(dst + 8) = o1;
  }
}

// ---------- k3s: layer-1 attention -> catT bf16 [bb][kcol160][j512] + e-partials ---
__global__ __launch_bounds__(256) void k3s(const unsigned short* __restrict__ whT,
                                           const float* __restrict__ e1,
                                           const float* __restrict__ e2,
                                           const u64* __restrict__ maskw,
                                           const float* __restrict__ wv1,
                                           const float* __restrict__ wv2,
                                           unsigned short* __restrict__ catT,
                                           float* __restrict__ e1p,
                                           float* __restrict__ e2p) {
  __shared__ __align__(16) float e2s[N_];
  __shared__ __align__(16) float red[4][64][17];
  int x = (int)((blockIdx.x & 7) * 384 + (blockIdx.x >> 3));  // bijective (3072%8==0)
  const int hh = x >> 10;
  const int bb = (x >> 5) & 31;
  const int rg = x & 31;
  const int n0 = rg * 16;
  const int t = threadIdx.x;
  const int l = t & 63, wid = t >> 6;
  const int q = l >> 4, rl = l & 15;

  const float* e2pp = e2 + ((size_t)hh * B_ + bb) * N_;
  for (int i = t; i < N_ / 4; i += 256) ((float4*)e2s)[i] = ((const float4*)e2pp)[i];
  __syncthreads();

  const int row = n0 + rl;
  const float e1r = e1[((size_t)hh * B_ + bb) * N_ + row];
  const u64* mr = maskw + ((size_t)bb * N_ + row) * 8;

  f32x4 acc[4];
  #pragma unroll
  for (int c = 0; c < 4; ++c) acc[c] = (f32x4){0.f, 0.f, 0.f, 0.f};
  const unsigned short* wb = whT + ((size_t)hh * B_ + bb) * 64 * 512;

  #pragma unroll
  for (int tts = 0; tts < 2; ++tts) {
    const int tt = wid * 2 + tts;
    short8 bf[4][2];
    #pragma unroll
    for (int c = 0; c < 4; ++c) {
      const unsigned short* bp = wb + (size_t)(c * 16 + rl) * 512 + tt * 64 + q * 8;
      bf[c][0] = *(const short8*)bp;
      bf[c][1] = *(const short8*)(bp + 32);
    }
    u64 word = mr[tt];
    short8 af0 = build_af(e2s, e1r, word, tt * 64 + q * 8, q * 8);
    short8 af1 = build_af(e2s, e1r, word, tt * 64 + 32 + q * 8, 32 + q * 8);
    #pragma unroll
    for (int c = 0; c < 4; ++c) {
      acc[c] = __builtin_amdgcn_mfma_f32_16x16x32_bf16(af0, bf[c][0], acc[c], 0, 0, 0);
      acc[c] = __builtin_amdgcn_mfma_f32_16x16x32_bf16(af1, bf[c][1], acc[c], 0, 0, 0);
    }
  }

  #pragma unroll
  for (int c = 0; c < 4; ++c)
    #pragma unroll
    for (int r = 0; r < 4; ++r) red[wid][l][c * 4 + r] = acc[c][r];
  __syncthreads();

  if (wid == 0) {
    #pragma unroll
    for (int c = 0; c < 4; ++c)
      #pragma unroll
      for (int r = 0; r < 4; ++r)
        acc[c][r] = red[0][l][c * 4 + r] + red[1][l][c * 4 + r] +
                    red[2][l][c * 4 + r] + red[3][l][c * 4 + r];
    float w1c[4], w2c[4];
    #pragma unroll
    for (int c = 0; c < 4; ++c) {
      const int col = c * 16 + rl;
      w1c[c] = (col < FH_) ? wv1[hh * FH_ + col] : 0.f;
      w2c[c] = (col < FH_) ? wv2[hh * FH_ + col] : 0.f;
    }
    #pragma unroll
    for (int r = 0; r < 4; ++r) {
      float srow = __shfl(acc[3][r], (q << 4) | 15);  // col 63 = denom (ones col)
      float invr = srow > 0.f ? 1.f / srow : 0.f;
      const int jrow = n0 + q * 4 + r;
      const size_t grow = (size_t)bb * N_ + jrow;
      float p1 = 0.f, p2 = 0.f;
      #pragma unroll
      for (int c = 0; c < 4; ++c) {
        const int col = c * 16 + rl;
        if (col < FH_) {
          float v = acc[c][r] * invr;
          v = v > 0.f ? v : __expf(v) - 1.f;  // ELU
          catT[((size_t)bb * KP_ + hh * FH_ + col) * 512 + jrow] = f2bf(v);
          p1 += v * w1c[c];
          p2 += v * w2c[c];
        }
      }
      p1 += __shfl_xor(p1, 1); p1 += __shfl_xor(p1, 2);
      p1 += __shfl_xor(p1, 4); p1 += __shfl_xor(p1, 8);
      p2 += __shfl_xor(p2, 1); p2 += __shfl_xor(p2, 2);
      p2 += __shfl_xor(p2, 4); p2 += __shfl_xor(p2, 8);
      if (rl == 0) {
        e1p[(size_t)hh * (B_ * N_) + grow] = p1;
        e2p[(size_t)hh * (B_ * N_) + grow] = p2;
      }
    }
  }
  if (hh == 2 && t < 16) {  // pad kcols 150..158 = 0, 159 = 1 (denominator)
    const int j = n0 + t;
    #pragma unroll
    for (int kc = CAT_; kc < KP_; ++kc)
      catT[((size_t)bb * KP_ + kc) * 512 + j] = (kc == KP_ - 1) ? (unsigned short)0x3f80 : 0;
  }
}

// ---------- kC: out = (P . catT) @ Wout / denom  (k4+k5 fused) --------------------
__global__ __launch_bounds__(256) void kC(const unsigned short* __restrict__ catT,
                                          const unsigned short* __restrict__ WoutT,
                                          const float* __restrict__ e1p,
                                          const float* __restrict__ e2p,
                                          const u64* __restrict__ maskw,
                                          float* __restrict__ out) {
  __shared__ __align__(16) float e2s[N_];
  __shared__ __align__(16) float red[3][64][41];
  __shared__ __align__(16) unsigned short pA[16 * 168];
  __shared__ float denomLDS[16];
  int x = (int)((blockIdx.x & 7) * 128 + (blockIdx.x >> 3));
  const int rg = x & 31;
  const int bb = x >> 5;
  const int n0 = rg * 16;
  const int t = threadIdx.x;
  const int l = t & 63, wid = t >> 6;
  const int q = l >> 4, rl = l & 15;

  for (int i = t; i < N_ / 4; i += 256) {
    float4 v0 = ((const float4*)(e2p))[(size_t)bb * 128 + i];
    float4 v1 = ((const float4*)(e2p + B_ * N_))[(size_t)bb * 128 + i];
    float4 v2 = ((const float4*)(e2p + 2 * B_ * N_))[(size_t)bb * 128 + i];
    float4 s;
    s.x = v0.x + v1.x + v2.x; s.y = v0.y + v1.y + v2.y;
    s.z = v0.z + v1.z + v2.z; s.w = v0.w + v1.w + v2.w;
    ((float4*)e2s)[i] = s;
  }
  __syncthreads();

  const int row = n0 + rl;
  const size_t gr = (size_t)bb * N_ + row;
  const float e1r = e1p[gr] + e1p[B_ * N_ + gr] + e1p[2 * B_ * N_ + gr];
  const u64* mr = maskw + gr * 8;

  f32x4 acc[10];
  #pragma unroll
  for (int c = 0; c < 10; ++c) acc[c] = (f32x4){0.f, 0.f, 0.f, 0.f};
  const unsigned short* cb = catT + (size_t)bb * KP_ * 512;

  #pragma unroll
  for (int tts = 0; tts < 2; ++tts) {
    const int tt = wid * 2 + tts;
    u64 word = mr[tt];
    short8 af0 = build_af(e2s, e1r, word, tt * 64 + q * 8, q * 8);
    short8 af1 = build_af(e2s, e1r, word, tt * 64 + 32 + q * 8, 32 + q * 8);
    #pragma unroll
    for (int c = 0; c < 10; ++c) {
      const unsigned short* bp = cb + (size_t)(c * 16 + rl) * 512 + tt * 64 + q * 8;
      short8 b0 = *(const short8*)bp;
      short8 b1 = *(const short8*)(bp + 32);
      acc[c] = __builtin_amdgcn_mfma_f32_16x16x32_bf16(af0, b0, acc[c], 0, 0, 0);
      acc[c] = __builtin_amdgcn_mfma_f32_16x16x32_bf16(af1, b1, acc[c], 0, 0, 0);
    }
  }

  if (wid > 0) {
    #pragma unroll
    for (int c = 0; c < 10; ++c)
      #pragma unroll
      for (int r = 0; r < 4; ++r) red[wid - 1][l][c * 4 + r] = acc[c][r];
  }
  __syncthreads();

  if (wid == 0) {
    #pragma unroll
    for (int c = 0; c < 10; ++c)
      #pragma unroll
      for (int r = 0; r < 4; ++r) {
        const int idx = c * 4 + r;
        acc[c][r] += red[0][l][idx] + red[1][l][idx] + red[2][l][idx];
      }
    // Pcat -> bf16 LDS A-tile [16][168]; denom = kcol 159 (f32 exact)
    #pragma unroll
    for (int c = 0; c < 10; ++c)
      #pragma unroll
      for (int r = 0; r < 4; ++r)
        pA[(q * 4 + r) * 168 + c * 16 + rl] = f2bf(acc[c][r]);
    if (rl == 15) {
      #pragma unroll
      for (int r = 0; r < 4; ++r) denomLDS[q * 4 + r] = acc[9][r];
    }
  }
  __syncthreads();

  if (wid == 0) {  // second GEMM: 16x160 @ 160x80 (WoutT frags, same as old k4)
    short8 af2[5];
    #pragma unroll
    for (int ks = 0; ks < 5; ++ks)
      af2[ks] = *(const short8*)&pA[rl * 168 + ks * 32 + q * 8];
    f32x4 acc2[5];
    #pragma unroll
    for (int nt = 0; nt < 5; ++nt) acc2[nt] = (f32x4){0.f, 0.f, 0.f, 0.f};
    #pragma unroll
    for (int ks = 0; ks < 5; ++ks)
      #pragma unroll
      for (int nt = 0; nt < 5; ++nt)
        acc2[nt] = __builtin_amdgcn_mfma_f32_16x16x32_bf16(
            af2[ks],
            *(const short8*)&WoutT[(size_t)(nt * 16 + rl) * KP_ + ks * 32 + q * 8],
            acc2[nt], 0, 0, 0);
    #pragma unroll
    for (int r = 0; r < 4; ++r) {
      const float dv = denomLDS[q * 4 + r];
      const float invr = dv > 0.f ? 1.f / dv : 0.f;
      const size_t ob = ((size_t)bb * N_ + n0 + q * 4 + r) * FO_;
      #pragma unroll
      for (int nt = 0; nt < 5; ++nt) out[ob + nt * 16 + rl] = acc2[nt][r] * invr;
    }
  }
}

extern "C" void kernel_launch(void* const* d_in, const int* in_sizes, int n_in,
                              void* d_out, int out_size, void* d_ws, size_t ws_size,
                              hipStream_t stream) {
  const float* h    = (const float*)d_in[0];
  const int*   adj  = (const int*)d_in[1];
  const float* Ws   = (const float*)d_in[2];
  const float* aa   = (const float*)d_in[3];
  const float* Wout = (const float*)d_in[4];
  const float* aout = (const float*)d_in[5];

  char* ws = (char*)d_ws;
  unsigned short* whT   = (unsigned short*)(ws + 0);         // 6,291,456
  float* e1h            = (float*)(ws + 6291456);            //   196,608
  float* e2h            = (float*)(ws + 6488064);            //   196,608
  u64*   mk             = (u64*)  (ws + 6684672);            // 1,048,576
  unsigned short* catT  = (unsigned short*)(ws + 7733248);   // 5,242,880
  unsigned short* WoutT = (unsigned short*)(ws + 12976128);  //    30,720
  float* wv1            = (float*)(ws + 13008896);           //     1,024
  float* wv2            = (float*)(ws + 13009920);           //     1,024
  float* e1p            = (float*)(ws + 13010944);           //   196,608
  float* e2p            = (float*)(ws + 13207552);           //   196,608

  hipLaunchKernelGGL(kA, dim3(2832), dim3(256), 0, stream,
                     h, adj, Ws, aa, Wout, aout, whT, e1h, e2h, mk, WoutT, wv1, wv2);
  hipLaunchKernelGGL(k3s, dim3(3072), dim3(256), 0, stream,
                     whT, e1h, e2h, mk, wv1, wv2, catT, e1p, e2p);
  hipLaunchKernelGGL(kC, dim3(1024), dim3(256), 0, stream,
                     catT, WoutT, e1p, e2p, mk, (float*)d_out);
}